// Round 8
// baseline (830.739 us; speedup 1.0000x reference)
//
#include <hip/hip_runtime.h>
#include <hip/hip_fp16.h>

#define TT 2048
#define BB 128
#define II 32
#define HH 128
#define NW (TT / 8)

typedef float v2f __attribute__((ext_vector_type(2)));
typedef float v4f __attribute__((ext_vector_type(4)));
typedef unsigned int u32;

// packed dual fp32 FMA (VOP3P)
__device__ __forceinline__ v2f pk_fma(v2f a, v2f b, v2f c) {
    v2f d;
    asm("v_pk_fma_f32 %0, %1, %2, %3" : "=v"(d) : "v"(a), "v"(b), "v"(c));
    return d;
}
// DPP ctrl: 0xB1 quad xor1, 0x4E quad xor2,
// 0x104 row_shl:4 (lane i <- i+4), 0x114 row_shr:4 (lane i <- i-4),
// 0x128 row_ror:8 (== xor8 within 16 lanes)
template <int CTRL>
__device__ __forceinline__ float dpp_mov(float p) {
    return __int_as_float(__builtin_amdgcn_update_dpp(0, __float_as_int(p), CTRL, 0xF, 0xF, true));
}
template <int CTRL>
__device__ __forceinline__ float dpp_add(float p) { return p + dpp_mov<CTRL>(p); }
template <int CTRL>
__device__ __forceinline__ float pair_red(float x, float y, bool sel) {
    float keep = sel ? y : x;
    float give = sel ? x : y;
    return keep + dpp_mov<CTRL>(give);
}
__device__ __forceinline__ void unpack2(u32 u, float& lo, float& hi) {
    lo = __half2float(__ushort_as_half((unsigned short)u));
    hi = __half2float(__ushort_as_half((unsigned short)(u >> 16)));
}

// 4 waves x 64 lanes, one block per batch element, 1 wave/SIMD.
// R6 skeleton (8 rows per 16-lane group, DPP reduce-scatter) with the h
// exchange shrunk: h stored in LDS as FP16 (|h|<=1, abs err ~1.2e-4) so each
// lane's 8 cols are ONE ds_read_b128; writes are b16. X lives in registers
// (global loads one 8-step window ahead, compiler-counted vmcnt) - no LDS X
// staging, no global_load_lds, all waves symmetric at the barrier.
// Per-CU per-step LDS ops: 4 reads + 4 b16 writes (was ~16 ops).
__global__ __launch_bounds__(256, 1)
void vrnn_kernel(const float* __restrict__ X, const float* __restrict__ W_in,
                 const float* __restrict__ W_hh, const float* __restrict__ rnn_bias,
                 const float* __restrict__ alpha, const float* __restrict__ value_W,
                 const float* __restrict__ value_bias, float* __restrict__ out)
{
    const int b    = blockIdx.x;
    const int tid  = threadIdx.x;
    const int wave = tid >> 6;        // 0..3
    const int lane = tid & 63;
    const int g    = lane >> 4;       // 0..3
    const int j    = lane & 15;       // 0..15
    const int base = 32 * wave + 8 * g;
    const int rown = base + (j & 7);  // this lane's output row

    __shared__ __align__(16) __half hbuf[2][160];   // padded f16 h, ping-pong
    __shared__ __align__(16) float  vres[TT];       // 8 KB V staging

    // ---- issue window-0 X loads first (hide HBM latency under weight loads)
    v2f xa[8], xb[8];
#pragma unroll
    for (int s = 0; s < 8; ++s)
        xa[s] = *(const v2f*)(X + (size_t)s * (BB * II) + b * II + 2 * j);

    const float SC = 2.8853900817779268f;   // 2*log2(e) prescale for tanh

    // ---- per-lane constants (prescaled) ----
    v2f wh[8][4], wi8[8], binit[8];
#pragma unroll
    for (int r = 0; r < 8; ++r) {
        const float* wr = W_hh + (size_t)(base + r) * HH + 8 * j;
        v4f a0 = *(const v4f*)(wr);
        v4f a1 = *(const v4f*)(wr + 4);
        wh[r][0] = (v2f){a0.x * SC, a0.y * SC}; wh[r][1] = (v2f){a0.z * SC, a0.w * SC};
        wh[r][2] = (v2f){a1.x * SC, a1.y * SC}; wh[r][3] = (v2f){a1.z * SC, a1.w * SC};
        v2f wiv  = *(const v2f*)(W_in + (size_t)(base + r) * II + 2 * j);
        wi8[r]   = (v2f){wiv.x * SC, wiv.y * SC};
        binit[r] = (v2f){ (j == 0) ? rnn_bias[base + r] * SC : 0.0f, 0.0f };
    }
    v2f vwc[4];
#pragma unroll
    for (int i = 0; i < 4; ++i) vwc[i] = *(const v2f*)(value_W + 8 * j + 2 * i);
    const float al_own = alpha[rown];
    const float vb     = value_bias[0];
    const bool  b0 = (j & 1) != 0;
    const bool  b1 = (j & 2) != 0;
    const bool  b2 = (j & 4) != 0;
    // half-granular offsets; +16-half pad per 8 chunks keeps banking <=2-way
    const int   roff_h = 8 * j + 16 * (j >> 3);
    const int   woff_h = 8 * (rown >> 3) + 16 * (rown >> 6) + (rown & 7);

    float hreg = 0.0f;
    float hpre = 0.0f;                 // (1-al)*hreg maintained off-path

    if (tid < 160) ((u32*)hbuf)[tid] = 0u;   // zero both h buffers
    __syncthreads();

    float* outV = out;
    float* outH = out + (size_t)TT * BB;

#define STEP(W_, S_, XARR)                                                     \
    {                                                                          \
        const int t   = 8 * (W_) + (S_);                                       \
        const int par = (S_) & 1;                                              \
        const __half* hb = &hbuf[par ^ 1][roff_h];                             \
        const v4f hv = *(const v4f*)hb;                                        \
        float h0, h1, h2, h3, h4, h5, h6, h7;                                  \
        unpack2(__float_as_uint(hv.x), h0, h1);                                \
        unpack2(__float_as_uint(hv.y), h2, h3);                                \
        unpack2(__float_as_uint(hv.z), h4, h5);                                \
        unpack2(__float_as_uint(hv.w), h6, h7);                                \
        v2f hp[4] = { (v2f){h0, h1}, (v2f){h2, h3},                            \
                      (v2f){h4, h5}, (v2f){h6, h7} };                          \
        float p[8];                                                            \
        _Pragma("unroll")                                                      \
        for (int r = 0; r < 8; ++r) {                                          \
            v2f a = pk_fma(wi8[r], XARR[S_], binit[r]);                        \
            a = pk_fma(wh[r][0], hp[0], a);                                    \
            a = pk_fma(wh[r][1], hp[1], a);                                    \
            a = pk_fma(wh[r][2], hp[2], a);                                    \
            a = pk_fma(wh[r][3], hp[3], a);                                    \
            p[r] = a.x + a.y;                                                  \
        }                                                                      \
        float q0 = pair_red<0xB1>(p[0], p[1], b0);                             \
        float q1 = pair_red<0xB1>(p[2], p[3], b0);                             \
        float q2 = pair_red<0xB1>(p[4], p[5], b0);                             \
        float q3 = pair_red<0xB1>(p[6], p[7], b0);                             \
        float r0 = pair_red<0x4E>(q0, q1, b1);                                 \
        float r1 = pair_red<0x4E>(q2, q3, b1);                                 \
        const float k3 = b2 ? r1 : r0;                                         \
        const float g3 = b2 ? r0 : r1;                                         \
        const float vL = dpp_mov<0x104>(g3);                                   \
        const float vR = dpp_mov<0x114>(g3);                                   \
        float pre = k3 + (b2 ? vR : vL);                                       \
        pre += dpp_mov<0x128>(pre);                                            \
        const float e  = __builtin_amdgcn_exp2f(pre);                          \
        const float rc = __builtin_amdgcn_rcpf(e + 1.0f);                      \
        const float gt = fmaf(-2.0f, rc, 1.0f);                                \
        hreg = fmaf(al_own, gt, hpre);                                         \
        hbuf[par][woff_h] = __float2half(hreg);                                \
        hpre = fmaf(-al_own, hreg, hreg);                                      \
        if (wave == ((S_) & 3) && t > 0) {                                     \
            v2f vt = vwc[0] * hp[0];                                           \
            vt = pk_fma(vwc[1], hp[1], vt);                                    \
            vt = pk_fma(vwc[2], hp[2], vt);                                    \
            vt = pk_fma(vwc[3], hp[3], vt);                                    \
            float vs = vt.x + vt.y;                                            \
            vs = dpp_add<0xB1>(vs);                                            \
            vs = dpp_add<0x4E>(vs);                                            \
            const float uL = dpp_mov<0x104>(vs);                               \
            const float uR = dpp_mov<0x114>(vs);                               \
            vs += b2 ? uR : uL;                                                \
            vs = dpp_add<0x128>(vs);                                           \
            if (lane == 0) vres[t - 1] = vb + vs;                              \
        }                                                                      \
        asm volatile("s_waitcnt lgkmcnt(0)" ::: "memory");                     \
        __builtin_amdgcn_s_barrier();                                          \
    }

    for (int w2 = 0; w2 < NW; w2 += 2) {
        // issue X loads for window w2+1 (consumed next half-iteration)
#pragma unroll
        for (int s = 0; s < 8; ++s) {
            const int trow = 8 * (w2 + 1) + s;
            xb[s] = *(const v2f*)(X + (size_t)trow * (BB * II) + b * II + 2 * j);
        }
#pragma unroll
        for (int s = 0; s < 8; ++s) STEP(w2, s, xa)
        // issue X loads for window w2+2
#pragma unroll
        for (int s = 0; s < 8; ++s) {
            int trow = 8 * (w2 + 2) + s;
            if (trow > TT - 1) trow = TT - 1;
            xa[s] = *(const v2f*)(X + (size_t)trow * (BB * II) + b * II + 2 * j);
        }
#pragma unroll
        for (int s = 0; s < 8; ++s) STEP(w2 + 1, s, xb)
    }
#undef STEP

    // ---- tail: V[T-1] from final h (parity 1), last_hidden, flush ----
    if (wave == 0) {
        const __half* hb = &hbuf[1][roff_h];
        const v4f hv = *(const v4f*)hb;
        float h0, h1, h2, h3, h4, h5, h6, h7;
        unpack2(__float_as_uint(hv.x), h0, h1);
        unpack2(__float_as_uint(hv.y), h2, h3);
        unpack2(__float_as_uint(hv.z), h4, h5);
        unpack2(__float_as_uint(hv.w), h6, h7);
        v2f hp[4] = { (v2f){h0, h1}, (v2f){h2, h3},
                      (v2f){h4, h5}, (v2f){h6, h7} };
        v2f vt = vwc[0] * hp[0];
        vt = pk_fma(vwc[1], hp[1], vt);
        vt = pk_fma(vwc[2], hp[2], vt);
        vt = pk_fma(vwc[3], hp[3], vt);
        float vs = vt.x + vt.y;
        vs = dpp_add<0xB1>(vs);
        vs = dpp_add<0x4E>(vs);
        const float uL = dpp_mov<0x104>(vs);
        const float uR = dpp_mov<0x114>(vs);
        vs += b2 ? uR : uL;
        vs = dpp_add<0x128>(vs);
        if (lane == 0) vres[TT - 1] = vb + vs;
    }
    if (j < 8)
        outH[(size_t)b * HH + rown] = hreg;   // hreg is f32 (full precision)
    __syncthreads();
#pragma unroll
    for (int i = 0; i < TT / 256; ++i)
        outV[(size_t)(i * 256 + tid) * BB + b] = vres[i * 256 + tid];
}

extern "C" void kernel_launch(void* const* d_in, const int* in_sizes, int n_in,
                              void* d_out, int out_size, void* d_ws, size_t ws_size,
                              hipStream_t stream) {
    const float* X      = (const float*)d_in[0];
    const float* W_in   = (const float*)d_in[1];
    const float* W_hh   = (const float*)d_in[2];
    const float* rbias  = (const float*)d_in[3];
    const float* alpha  = (const float*)d_in[4];
    const float* vW     = (const float*)d_in[5];
    const float* vbias  = (const float*)d_in[6];
    float* out = (float*)d_out;

    vrnn_kernel<<<dim3(BB), dim3(256), 0, stream>>>(X, W_in, W_hh, rbias, alpha, vW, vbias, out);
}

// Round 9
// 770.242 us; speedup vs baseline: 1.0785x; 1.0785x over previous
//
#include <hip/hip_runtime.h>

#define TT 2048
#define BB 128
#define II 32
#define HH 128
#define NW (TT / 8)

typedef float v2f __attribute__((ext_vector_type(2)));
typedef float v4f __attribute__((ext_vector_type(4)));
typedef unsigned int u32;
typedef __attribute__((address_space(3))) u32 lds_u32;
typedef const __attribute__((address_space(1))) u32 glb_u32;

// packed dual fp32 FMA (VOP3P)
__device__ __forceinline__ v2f pk_fma(v2f a, v2f b, v2f c) {
    v2f d;
    asm("v_pk_fma_f32 %0, %1, %2, %3" : "=v"(d) : "v"(a), "v"(b), "v"(c));
    return d;
}
// DPP ctrl: 0xB1 quad xor1, 0x4E quad xor2, 0x124 row_ror:4, 0x128 row_ror:8
template <int CTRL>
__device__ __forceinline__ float dpp_mov(float p) {
    return __int_as_float(__builtin_amdgcn_update_dpp(0, __float_as_int(p), CTRL, 0xF, 0xF, true));
}
template <int CTRL>
__device__ __forceinline__ float dpp_add(float p) { return p + dpp_mov<CTRL>(p); }
template <int CTRL>
__device__ __forceinline__ float pair_red(float x, float y, bool sel) {
    float keep = sel ? y : x;
    float give = sel ? x : y;
    return keep + dpp_mov<CTRL>(give);
}

// 4 waves x 64 lanes, 1 block/batch, 1 wave/SIMD. R6 skeleton with the
// post-barrier critical chain minimized:
//   chain = ds_read_b128 h -> 4 pk_fma -> xor1,xor2 (select-reduce) ->
//           ror4+ror8 plain adds (both row-partials, direction-insensitive)
//           -> 1 cndmask -> exp2 -> add -> rcp -> 1 fma -> ds_write_b32.
// wi*x+bias partials and hsum=al+(1-al)h are precomputed in the previous
// step's slack; V(t-1) reduced with plain dpp_add into LDS vres (no global
// stores / vmcnt pollution in the loop). Weights prescaled by 2*log2(e).
__global__ __launch_bounds__(256)
void vrnn_kernel(const float* __restrict__ X, const float* __restrict__ W_in,
                 const float* __restrict__ W_hh, const float* __restrict__ rnn_bias,
                 const float* __restrict__ alpha, const float* __restrict__ value_W,
                 const float* __restrict__ value_bias, float* __restrict__ out)
{
    const int b    = blockIdx.x;
    const int tid  = threadIdx.x;
    const int wave = tid >> 6;        // 0..3
    const int lane = tid & 63;
    const int g    = lane >> 4;       // 0..3
    const int j    = lane & 15;       // 0..15
    const int base = 32 * wave + 8 * g;

    __shared__ __align__(16) float xw[2][8][II];     // 2 KB X windows
    __shared__ __align__(16) float hbuf[2][192];     // 16 chunks x 12 floats
    __shared__ __align__(16) float vres[TT];         // 8 KB V staging

    // ---- stage window 0 early ----
    if (wave == 0) {
        const float* src = X + (size_t)(lane >> 3) * (BB * II) + b * II + (lane & 7) * 4;
        __builtin_amdgcn_global_load_lds((glb_u32*)src, (lds_u32*)(&xw[0][0][0]), 16, 0, 0);
    }

    const float SC = 2.8853900817779268f;   // 2*log2(e) prescale (e = exp2(pre))

    // ---- per-lane constants (prescaled) ----
    v2f wh[8][4], wi8[8], binit[8];
#pragma unroll
    for (int r = 0; r < 8; ++r) {
        const float* wr = W_hh + (size_t)(base + r) * HH + 8 * j;
        v4f a0 = *(const v4f*)(wr);
        v4f a1 = *(const v4f*)(wr + 4);
        wh[r][0] = (v2f){a0.x * SC, a0.y * SC}; wh[r][1] = (v2f){a0.z * SC, a0.w * SC};
        wh[r][2] = (v2f){a1.x * SC, a1.y * SC}; wh[r][3] = (v2f){a1.z * SC, a1.w * SC};
        v2f wiv  = *(const v2f*)(W_in + (size_t)(base + r) * II + 2 * j);
        wi8[r]   = (v2f){wiv.x * SC, wiv.y * SC};
        binit[r] = (v2f){ (j == 0) ? rnn_bias[base + r] * SC : 0.0f, 0.0f };
    }
    v2f vwc[4];
#pragma unroll
    for (int i = 0; i < 4; ++i) vwc[i] = *(const v2f*)(value_W + 8 * j + 2 * i);
    const bool  b0 = (j & 1) != 0;
    const bool  b1 = (j & 2) != 0;
    const bool  selhi = ((j >> 2) & 1) != 0;          // picks row-partial r1''
    const int   rown2 = base + (j & 3) + 4 * ((j >> 2) & 1);   // row this lane finalizes
    const float al_own = alpha[rown2];
    const float nal2   = -2.0f * al_own;
    const float oneml  = 1.0f - al_own;
    const float vb     = value_bias[0];
    const int   woff = 12 * (4 * wave + g) + (j & 3) + 4 * ((j >> 2) & 1);

    float hreg = 0.0f;
    float hsum = al_own;               // al + (1-al)*h_{-1},  h_{-1}=0
    v2f   xc_next;
    v2f   pinit[8];

    if (tid < 192) hbuf[1][tid] = 0.0f;   // h_{-1}=0 (t=0 reads buf 1)
    __syncthreads();

    float* outV = out;
    float* outH = out + (size_t)TT * BB;

#define STEP(S_)                                                               \
    {                                                                          \
        const int t   = 8 * w + (S_);                                          \
        const int par = (S_) & 1;                                              \
        /* post-barrier: h read first (critical) */                            \
        const float* hb = &hbuf[par ^ 1][12 * j];                              \
        const v4f h0v = *(const v4f*)(hb);                                     \
        const v4f h1v = *(const v4f*)(hb + 4);                                 \
        v2f pin[8];                                                            \
        if ((S_) == 0) {                                                       \
            const v2f xc0 = *(const v2f*)(&xw[w & 1][0][2 * j]);               \
            _Pragma("unroll")                                                  \
            for (int r = 0; r < 8; ++r) pin[r] = pk_fma(wi8[r], xc0, binit[r]);\
        } else {                                                               \
            _Pragma("unroll")                                                  \
            for (int r = 0; r < 8; ++r) pin[r] = pinit[r];                     \
        }                                                                      \
        v2f hp[4] = { (v2f){h0v.x, h0v.y}, (v2f){h0v.z, h0v.w},                \
                      (v2f){h1v.x, h1v.y}, (v2f){h1v.z, h1v.w} };              \
        float p[8];                                                            \
        _Pragma("unroll")                                                      \
        for (int r = 0; r < 8; ++r) {                                          \
            v2f a = pin[r];                                                    \
            a = pk_fma(wh[r][0], hp[0], a);                                    \
            a = pk_fma(wh[r][1], hp[1], a);                                    \
            a = pk_fma(wh[r][2], hp[2], a);                                    \
            a = pk_fma(wh[r][3], hp[3], a);                                    \
            p[r] = a.x + a.y;                                                  \
        }                                                                      \
        float q0 = pair_red<0xB1>(p[0], p[1], b0);                             \
        float q1 = pair_red<0xB1>(p[2], p[3], b0);                             \
        float q2 = pair_red<0xB1>(p[4], p[5], b0);                             \
        float q3 = pair_red<0xB1>(p[6], p[7], b0);                             \
        float r0 = pair_red<0x4E>(q0, q1, b1);                                 \
        float r1 = pair_red<0x4E>(q2, q3, b1);                                 \
        r0 = dpp_add<0x124>(r0);  r1 = dpp_add<0x124>(r1);                     \
        r0 = dpp_add<0x128>(r0);  r1 = dpp_add<0x128>(r1);                     \
        const float pre = selhi ? r1 : r0;                                     \
        const float e  = __builtin_amdgcn_exp2f(pre);                          \
        const float rc = __builtin_amdgcn_rcpf(e + 1.0f);                      \
        hreg = fmaf(nal2, rc, hsum);                                           \
        hbuf[par][woff] = hreg;                                                \
        /* ---- slack ---- */                                                  \
        hsum = fmaf(oneml, hreg, al_own);                                      \
        if (wave == ((S_) & 3) && ((w | (S_)) != 0)) {                         \
            v2f vt = vwc[0] * hp[0];                                           \
            vt = pk_fma(vwc[1], hp[1], vt);                                    \
            vt = pk_fma(vwc[2], hp[2], vt);                                    \
            vt = pk_fma(vwc[3], hp[3], vt);                                    \
            float vs = vt.x + vt.y;                                            \
            vs = dpp_add<0xB1>(vs);                                            \
            vs = dpp_add<0x4E>(vs);                                            \
            vs = dpp_add<0x124>(vs);                                           \
            vs = dpp_add<0x128>(vs);                                           \
            if (lane == 0) vres[t - 1] = vb + vs;                              \
        }                                                                      \
        if ((S_) < 7) {                                                        \
            xc_next = *(const v2f*)(&xw[w & 1][(S_) + 1][2 * j]);              \
            _Pragma("unroll")                                                  \
            for (int r = 0; r < 8; ++r)                                        \
                pinit[r] = pk_fma(wi8[r], xc_next, binit[r]);                  \
        }                                                                      \
        if (wave == 0 && (S_) == 7)                                            \
            asm volatile("s_waitcnt vmcnt(0)" ::: "memory");                   \
        asm volatile("s_waitcnt lgkmcnt(0)" ::: "memory");                     \
        __builtin_amdgcn_s_barrier();                                          \
    }

    for (int w = 0; w < NW; ++w) {
        if (wave == 0 && w + 1 < NW) {
            const float* src = X + (size_t)((w + 1) * 8 + (lane >> 3)) * (BB * II)
                                 + b * II + (lane & 7) * 4;
            __builtin_amdgcn_global_load_lds((glb_u32*)src,
                (lds_u32*)(&xw[(w + 1) & 1][0][0]), 16, 0, 0);
        }
        STEP(0) STEP(1) STEP(2) STEP(3) STEP(4) STEP(5) STEP(6) STEP(7)
    }
#undef STEP

    // ---- tail: V[T-1] from final h (parity 1), last_hidden, flush ----
    if (wave == 0) {
        const float* hb = &hbuf[1][12 * j];
        const v4f h0v = *(const v4f*)(hb);
        const v4f h1v = *(const v4f*)(hb + 4);
        v2f hp[4] = { (v2f){h0v.x, h0v.y}, (v2f){h0v.z, h0v.w},
                      (v2f){h1v.x, h1v.y}, (v2f){h1v.z, h1v.w} };
        v2f vt = vwc[0] * hp[0];
        vt = pk_fma(vwc[1], hp[1], vt);
        vt = pk_fma(vwc[2], hp[2], vt);
        vt = pk_fma(vwc[3], hp[3], vt);
        float vs = vt.x + vt.y;
        vs = dpp_add<0xB1>(vs);
        vs = dpp_add<0x4E>(vs);
        vs = dpp_add<0x124>(vs);
        vs = dpp_add<0x128>(vs);
        if (lane == 0) vres[TT - 1] = vb + vs;
    }
    if (j < 8)                                   // rown2 == base + j for j<8
        outH[(size_t)b * HH + base + j] = hreg;
    __syncthreads();
#pragma unroll
    for (int i = 0; i < TT / 256; ++i)
        outV[(size_t)(i * 256 + tid) * BB + b] = vres[i * 256 + tid];
}

extern "C" void kernel_launch(void* const* d_in, const int* in_sizes, int n_in,
                              void* d_out, int out_size, void* d_ws, size_t ws_size,
                              hipStream_t stream) {
    const float* X      = (const float*)d_in[0];
    const float* W_in   = (const float*)d_in[1];
    const float* W_hh   = (const float*)d_in[2];
    const float* rbias  = (const float*)d_in[3];
    const float* alpha  = (const float*)d_in[4];
    const float* vW     = (const float*)d_in[5];
    const float* vbias  = (const float*)d_in[6];
    float* out = (float*)d_out;

    vrnn_kernel<<<dim3(BB), dim3(256), 0, stream>>>(X, W_in, W_hh, rbias, alpha, vW, vbias, out);
}